// Round 3
// baseline (201.356 us; speedup 1.0000x reference)
//
#include <hip/hip_runtime.h>
#include <math.h>

// Problem constants
#define BB 8
#define LL 1024
#define SS 1024
#define CC 128
#define NN 8
#define PP 256

static constexpr float EPS       = 1e-6f;
static constexpr float ONE_M_EPS = 1.0f - 1e-6f;
static constexpr float INV_T     = 1.0f / 0.07f;
static constexpr float NLL_MAX   = 13.815511f;    // -log(1e-6)
static constexpr float NLL_MIN   = 1.0000005e-6f; // -log(1-1e-6)

// Workspace layout (float offsets). No dot array anymore (recompute strategy).
static constexpr size_t OFF_LSER   = 0;                      // B*L
static constexpr size_t OFF_LSEC   = 8192;                   // B*S
static constexpr size_t OFF_SHARP2 = 16384;                  // B*L
static constexpr size_t OFF_RP     = 24576;                  // rowpart: 8*16*1024*4 floats
static constexpr size_t OFF_CP     = OFF_RP + 524288;        // colpart: 8*32*1024*4 floats
static constexpr size_t OFF_ACC    = OFF_CP + 1048576;       // B*6
static constexpr size_t OFF_ACCCL  = OFF_ACC + 48;           // 2
static constexpr size_t OFF_QN     = OFF_ACC + 64;           // 8*128 normalized q_sel

// Output layout (floats): sharp1[8192], cl_pos_save[1024], total, geo_pos, geo_neg, loss_sharp, loss_cl
static constexpr int OUT_CLSAVE = 8192;
static constexpr int OUT_SCAL   = 9216;

typedef __bf16 bf16x8 __attribute__((ext_vector_type(8)));
typedef float  floatx4 __attribute__((ext_vector_type(4)));

__device__ __forceinline__ bf16x8 mkfrag(unsigned a, unsigned b, unsigned c, unsigned d) {
    uint4 t = make_uint4(a, b, c, d);
    return __builtin_bit_cast(bf16x8, t);
}

// Split 4 fp32 into packed bf16 hi pairs (RNE) + lo pairs (exact residual).
__device__ __forceinline__ void split_f4(float4 x,
                                         unsigned& hp0, unsigned& hp1,
                                         unsigned& lp0, unsigned& lp1) {
    unsigned u0 = __builtin_bit_cast(unsigned, x.x);
    unsigned u1 = __builtin_bit_cast(unsigned, x.y);
    unsigned u2 = __builtin_bit_cast(unsigned, x.z);
    unsigned u3 = __builtin_bit_cast(unsigned, x.w);
    unsigned r0 = u0 + 0x7FFFu + ((u0 >> 16) & 1u);
    unsigned r1 = u1 + 0x7FFFu + ((u1 >> 16) & 1u);
    unsigned r2 = u2 + 0x7FFFu + ((u2 >> 16) & 1u);
    unsigned r3 = u3 + 0x7FFFu + ((u3 >> 16) & 1u);
    float s0 = x.x - __builtin_bit_cast(float, r0 & 0xFFFF0000u);
    float s1 = x.y - __builtin_bit_cast(float, r1 & 0xFFFF0000u);
    float s2 = x.z - __builtin_bit_cast(float, r2 & 0xFFFF0000u);
    float s3 = x.w - __builtin_bit_cast(float, r3 & 0xFFFF0000u);
    hp0 = __builtin_amdgcn_perm(r1, r0, 0x07060302u);
    hp1 = __builtin_amdgcn_perm(r3, r2, 0x07060302u);
    lp0 = __builtin_amdgcn_perm(__builtin_bit_cast(unsigned, s1),
                                __builtin_bit_cast(unsigned, s0), 0x07060302u);
    lp1 = __builtin_amdgcn_perm(__builtin_bit_cast(unsigned, s3),
                                __builtin_bit_cast(unsigned, s2), 0x07060302u);
}

// Compute one 32x64 dot tile into acc[2][4] (fp32x4 frags). Deterministic: used
// identically by both passes so recomputed values are bitwise equal.
__device__ __forceinline__ void gemm_tile(const float* __restrict__ Ab,
                                          const float* __restrict__ Bb,
                                          int fl, int quad, floatx4 acc[2][4]) {
#pragma unroll
    for (int i = 0; i < 2; i++)
#pragma unroll
        for (int j = 0; j < 4; j++) acc[i][j] = (floatx4){0.f, 0.f, 0.f, 0.f};

    for (int c0 = 0; c0 < 128; c0 += 32) {
        float4 ax[2][2], bx[4][2];
#pragma unroll
        for (int mt = 0; mt < 2; mt++) {
            const float* p = Ab + (size_t)(mt * 16 + fl) * CC + c0 + quad * 8;
            ax[mt][0] = *(const float4*)p;
            ax[mt][1] = *(const float4*)(p + 4);
        }
#pragma unroll
        for (int nt = 0; nt < 4; nt++) {
            const float* p = Bb + (size_t)(nt * 16 + fl) * CC + c0 + quad * 8;
            bx[nt][0] = *(const float4*)p;
            bx[nt][1] = *(const float4*)(p + 4);
        }
        bf16x8 ah[2], al[2];
#pragma unroll
        for (int mt = 0; mt < 2; mt++) {
            unsigned h0, h1, h2, h3, q0, q1, q2, q3;
            split_f4(ax[mt][0], h0, h1, q0, q1);
            split_f4(ax[mt][1], h2, h3, q2, q3);
            ah[mt] = mkfrag(h0, h1, h2, h3);
            al[mt] = mkfrag(q0, q1, q2, q3);
        }
#pragma unroll
        for (int nt = 0; nt < 4; nt++) {
            unsigned h0, h1, h2, h3, q0, q1, q2, q3;
            split_f4(bx[nt][0], h0, h1, q0, q1);
            split_f4(bx[nt][1], h2, h3, q2, q3);
            bf16x8 bh = mkfrag(h0, h1, h2, h3);
            bf16x8 bl = mkfrag(q0, q1, q2, q3);
#pragma unroll
            for (int mt = 0; mt < 2; mt++) {
                acc[mt][nt] = __builtin_amdgcn_mfma_f32_16x16x32_bf16(ah[mt], bh, acc[mt][nt], 0, 0, 0);
                acc[mt][nt] = __builtin_amdgcn_mfma_f32_16x16x32_bf16(ah[mt], bl, acc[mt][nt], 0, 0, 0);
                acc[mt][nt] = __builtin_amdgcn_mfma_f32_16x16x32_bf16(al[mt], bh, acc[mt][nt], 0, 0, 0);
            }
        }
    }
}

// ---------------- K1: stats-only GEMM pass (blocks 0..1023) + prep (block 1024) ----------------
// 32x64 tile per wave -> 4096 waves. No dot store; only row/col tile partials.
__global__ __launch_bounds__(256) void gemm_stats(const float* __restrict__ A,
                                                  const float* __restrict__ Bm,
                                                  const float* __restrict__ q_cl,
                                                  const float* __restrict__ cl_pos,
                                                  const int* __restrict__ idx,
                                                  float* __restrict__ out,
                                                  float* __restrict__ ws) {
    int tid  = threadIdx.x;
    int lane = tid & 63;
    int w    = tid >> 6;

    if (blockIdx.x == 1024) {
        // ---- prep: zero accumulators, normalize q_sel, write cl_pos_save ----
        if (tid < 52) ws[OFF_ACC + tid] = 0.0f;
        for (int n = w; n < NN; n += 4) {
            int in = idx[n];
            const float* q = q_cl + ((size_t)(n * PP + in)) * CC;
            float2 qv = *(const float2*)(q + 2 * lane);
            float ss = qv.x * qv.x + qv.y * qv.y;
            for (int o = 32; o; o >>= 1) ss += __shfl_xor(ss, o);
            float inv = 1.0f / fmaxf(sqrtf(ss), 1e-12f);
            *(float2*)(ws + OFF_QN + n * 128 + 2 * lane) = make_float2(qv.x * inv, qv.y * inv);
            const float* cp = cl_pos + ((size_t)(n * PP + in)) * CC;
            float2 cv = *(const float2*)(cp + 2 * lane);
            *(float2*)(out + OUT_CLSAVE + n * 128 + 2 * lane) = cv;
        }
        return;
    }

    int t    = blockIdx.x * 4 + w;      // 0..4095
    int b    = t >> 9;
    int rem  = t & 511;
    int lt   = rem >> 4, st = rem & 15; // lt 0..31, st 0..15
    int l0   = lt * 32, s0 = st * 64;
    int fl   = lane & 15;
    int quad = lane >> 4;

    floatx4 acc[2][4];
    gemm_tile(A + ((size_t)b * LL + l0) * CC, Bm + ((size_t)b * SS + s0) * CC, fl, quad, acc);

    // ---- row tile stats (rows l0..l0+31, over 64 in-tile cols) ----
    float ces[4], cmx[4], csm[4], csq[4];
#pragma unroll
    for (int nt = 0; nt < 4; nt++) { ces[nt] = 0.f; cmx[nt] = -1e30f; csm[nt] = 0.f; csq[nt] = 0.f; }
#pragma unroll
    for (int mt = 0; mt < 2; mt++) {
#pragma unroll
        for (int r = 0; r < 4; r++) {
            float es = 0.f, mx = -1e30f, sm = 0.f, sq = 0.f;
#pragma unroll
            for (int nt = 0; nt < 4; nt++) {
                float d  = acc[mt][nt][r];
                float e  = __expf(d * INV_T);
                float s2 = fmaf(0.5f, d, 0.5f);
                es += e; mx = fmaxf(mx, s2); sm += s2; sq += s2 * s2;
                ces[nt] += e; cmx[nt] = fmaxf(cmx[nt], s2); csm[nt] += s2; csq[nt] += s2 * s2;
            }
            for (int o = 1; o < 16; o <<= 1) {
                es += __shfl_xor(es, o);
                mx = fmaxf(mx, __shfl_xor(mx, o));
                sm += __shfl_xor(sm, o);
                sq += __shfl_xor(sq, o);
            }
            if (fl == 0) {
                int row = l0 + mt * 16 + quad * 4 + r;
                *(float4*)(ws + OFF_RP + (((size_t)(b * 16 + st)) * 1024 + row) * 4) =
                    make_float4(es, mx, sm, sq);
            }
        }
    }
    // ---- col tile stats (cols s0..s0+63, over 32 in-tile rows) ----
#pragma unroll
    for (int nt = 0; nt < 4; nt++) {
        float es = ces[nt], mx = cmx[nt], sm = csm[nt], sq = csq[nt];
        for (int o = 16; o < 64; o <<= 1) {
            es += __shfl_xor(es, o);
            mx = fmaxf(mx, __shfl_xor(mx, o));
            sm += __shfl_xor(sm, o);
            sq += __shfl_xor(sq, o);
        }
        if (quad == 0) {
            int col = s0 + nt * 16 + fl;
            *(float4*)(ws + OFF_CP + (((size_t)(b * 32 + lt)) * 1024 + col) * 4) =
                make_float4(es, mx, sm, sq);
        }
    }
}

// ---------------- K2: blocks 0..15 combine+softmax; blocks 16..527 contrast ----------------
__global__ __launch_bounds__(256) void mid(const float* __restrict__ cl_pos,
                                           const int* __restrict__ idx,
                                           float* __restrict__ ws,
                                           float* __restrict__ out) {
    int q   = blockIdx.x;
    int tid = threadIdx.x;
    int lane = tid & 63, wid = tid >> 6;

    if (q < 16) {
        bool docol = (q < 8);     // colpart (32 tiles) -> LSEC + sharp1(out); rowpart (16) -> LSER + SHARP2
        int b = q & 7;
        const float* part = ws + (docol ? (OFF_CP + (size_t)b * 32 * 1024 * 4)
                                        : (OFF_RP + (size_t)b * 16 * 1024 * 4));
        int ntile = docol ? 32 : 16;
        float* lse = ws + (docol ? OFF_LSEC : OFF_LSER) + (size_t)b * 1024;
        float zs[4];
        float mxall = -1e30f;
#pragma unroll
        for (int r = 0; r < 4; r++) {
            int i = tid + r * 256;
            float es = 0.f, mx = -1e30f, sm = 0.f, sq = 0.f;
            for (int t = 0; t < ntile; t++) {
                float4 v = *(const float4*)(part + ((size_t)t * 1024 + i) * 4);
                es += v.x; mx = fmaxf(mx, v.y); sm += v.z; sq += v.w;
            }
            float mean = sm * (1.0f / 1024.0f);
            float var  = (sq - sm * sm * (1.0f / 1024.0f)) * (1.0f / 1023.0f);
            zs[r] = (mx - mean) / sqrtf(fmaxf(var, 1e-30f));
            mxall = fmaxf(mxall, zs[r]);
            lse[i] = __logf(es);
        }
        __shared__ float sb[4];
        __shared__ float red;
        float mx = mxall;
        for (int o = 32; o; o >>= 1) mx = fmaxf(mx, __shfl_xor(mx, o));
        if (!lane) sb[wid] = mx;
        __syncthreads();
        if (tid == 0) red = fmaxf(fmaxf(sb[0], sb[1]), fmaxf(sb[2], sb[3]));
        __syncthreads();
        mx = red;
        float e[4]; float smv = 0.f;
#pragma unroll
        for (int r = 0; r < 4; r++) { e[r] = __expf(zs[r] - mx); smv += e[r]; }
        for (int o = 32; o; o >>= 1) smv += __shfl_xor(smv, o);
        __syncthreads();
        if (!lane) sb[wid] = smv;
        __syncthreads();
        if (tid == 0) red = sb[0] + sb[1] + sb[2] + sb[3];
        __syncthreads();
        float inv = 1.0f / red;
        float* dst = docol ? (out + (size_t)b * 1024) : (ws + OFF_SHARP2 + (size_t)b * 1024);
#pragma unroll
        for (int r = 0; r < 4; r++) dst[tid + r * 256] = e[r] * inv;
    } else {
        // ---- contrast: one wave per all_k row j ----
        int j = (q - 16) * 4 + wid;
        int m, p;
        if (j < NN) {
            m = j; p = idx[j];
        } else {
            int jj = j - NN;
            m = jj / (PP - 1);
            p = 1 + (jj - m * (PP - 1));
            if (p == idx[m]) p = 0;
        }
        const float* k = cl_pos + ((size_t)(m * PP + p)) * CC;
        float2 kv = *(const float2*)(k + 2 * lane);
        float ksq = kv.x * kv.x + kv.y * kv.y;
        for (int o = 32; o; o >>= 1) ksq += __shfl_xor(ksq, o);
        float invkn = 1.0f / fmaxf(sqrtf(ksq), 1e-12f);
        float pos = 0.0f, neg = 0.0f;
        if (j < NN) {
            const float2 qv = *(const float2*)(ws + OFF_QN + j * 128 + 2 * lane);
            float dt = qv.x * kv.x + qv.y * kv.y;
            for (int o = 32; o; o >>= 1) dt += __shfl_xor(dt, o);
            float sim = fminf(fmaxf(fmaf(0.5f * invkn, dt, 0.5f), EPS), ONE_M_EPS);
            pos = -__logf(sim);
        } else {
#pragma unroll
            for (int n = 0; n < NN; n++) {
                const float2 qv = *(const float2*)(ws + OFF_QN + n * 128 + 2 * lane);
                float dt = qv.x * kv.x + qv.y * kv.y;
                for (int o = 32; o; o >>= 1) dt += __shfl_xor(dt, o);
                float om = fminf(fmaxf(fmaf(-0.5f * invkn, dt, 0.5f), EPS), ONE_M_EPS);
                neg -= __logf(om);
            }
        }
        __shared__ float cb[2][4];
        if (!lane) { cb[0][wid] = pos; cb[1][wid] = neg; }
        __syncthreads();
        if (tid == 0) {
            float ps = cb[0][0] + cb[0][1] + cb[0][2] + cb[0][3];
            float ng = cb[1][0] + cb[1][1] + cb[1][2] + cb[1][3];
            if (ps != 0.0f) atomicAdd(ws + OFF_ACCCL + 0, ps);
            if (ng != 0.0f) atomicAdd(ws + OFF_ACCCL + 1, ng);
        }
    }
}

// ---------------- K3: recompute GEMM tile + elementwise loss (no dot array) ----------------
__device__ __forceinline__ void proc_elem(float d, int lab, float lcj, float sh1j,
                                          float lr, float s2v,
                                          float& posg, float& negg, float& l1, float& l2,
                                          float& negs, float& pcf) {
    float t = lr + lcj - d * (2.0f * INV_T);   // -log(conf_geo)
    float isPos = (lab == 1) ? 1.0f : 0.0f;
    float isNeg = 1.0f - isPos;
    float tp   = fminf(fmaxf(t, NLL_MIN), NLL_MAX);
    float simc = fminf(fmaxf(fmaf(0.5f, d, 0.5f), EPS), ONE_M_EPS);
    float om   = fminf(fmaxf(fmaf(-0.5f, d, 0.5f), EPS), ONE_M_EPS);   // 1-simc exactly
    float nll2 = -__logf(simc);
    float cf   = fminf(fmaxf(__expf(-t), EPS), ONE_M_EPS);
    float nllg = -__logf(1.0f - cf);
    float nlls = -__logf(om);
    posg += isPos * tp;
    l1   += isPos * nll2 * sh1j;
    l2   += isPos * nll2 * s2v;
    pcf  += isPos;
    negg += isNeg * nllg;
    negs += isNeg * nlls;
}

__global__ __launch_bounds__(256) void loss_recompute(const float* __restrict__ A,
                                                      const float* __restrict__ Bm,
                                                      const int* __restrict__ label,
                                                      const float* __restrict__ sharp1,
                                                      float* __restrict__ ws) {
    int tid  = threadIdx.x;
    int lane = tid & 63;
    int w    = tid >> 6;
    int t    = blockIdx.x * 4 + w;      // 0..4095 ; all 4 waves share b
    int b    = t >> 9;
    int rem  = t & 511;
    int lt   = rem >> 4, st = rem & 15;
    int l0   = lt * 32, s0 = st * 64;
    int fl   = lane & 15;
    int quad = lane >> 4;

    floatx4 acc[2][4];
    gemm_tile(A + ((size_t)b * LL + l0) * CC, Bm + ((size_t)b * SS + s0) * CC, fl, quad, acc);

    // per-row scalars (8 rows per lane) and per-col scalars (4 cols per lane)
    float lrv[2][4], s2v[2][4];
#pragma unroll
    for (int mt = 0; mt < 2; mt++)
#pragma unroll
        for (int r = 0; r < 4; r++) {
            int row = l0 + mt * 16 + quad * 4 + r;
            lrv[mt][r] = ws[OFF_LSER + (size_t)b * 1024 + row];
            s2v[mt][r] = ws[OFF_SHARP2 + (size_t)b * 1024 + row];
        }
    float lcv[4], sh1v[4];
#pragma unroll
    for (int nt = 0; nt < 4; nt++) {
        int col = s0 + nt * 16 + fl;
        lcv[nt]  = ws[OFF_LSEC + (size_t)b * 1024 + col];
        sh1v[nt] = sharp1[(size_t)b * 1024 + col];
    }

    float posg = 0, negg = 0, l1 = 0, l2 = 0, negs = 0, pcf = 0;
#pragma unroll
    for (int mt = 0; mt < 2; mt++)
#pragma unroll
        for (int r = 0; r < 4; r++) {
            int row = l0 + mt * 16 + quad * 4 + r;
            const int* lrow = label + ((size_t)(b * 1024 + row)) * 1024 + s0;
#pragma unroll
            for (int nt = 0; nt < 4; nt++) {
                int lab = lrow[nt * 16 + fl];
                proc_elem(acc[mt][nt][r], lab, lcv[nt], sh1v[nt], lrv[mt][r], s2v[mt][r],
                          posg, negg, l1, l2, negs, pcf);
            }
        }

    float vals[6] = {posg, negg, l1, l2, negs, pcf};
    __shared__ float sb[6][4];
#pragma unroll
    for (int k = 0; k < 6; k++) {
        float v = vals[k];
        for (int o = 32; o; o >>= 1) v += __shfl_xor(v, o);
        if (!lane) sb[k][w] = v;
    }
    __syncthreads();
    if (tid < 6) {
        float r = sb[tid][0] + sb[tid][1] + sb[tid][2] + sb[tid][3];
        atomicAdd(ws + OFF_ACC + (size_t)b * 6 + tid, r);
    }
}

// ---------------- K4: final scalar combine (1 block; kernel boundary = coherence) ----------------
__global__ void finalize(float* __restrict__ out, const float* __restrict__ ws) {
    if (threadIdx.x != 0) return;
    float gp = 0, gn = 0, lsh = 0;
    for (int b = 0; b < 8; b++) {
        const float* a = ws + OFF_ACC + (size_t)b * 6;
        float pc = a[5];
        float nc = (float)((size_t)LL * SS) - pc;
        gp += a[0] / fmaxf(pc, 1.0f);
        gn += a[1] / fmaxf(nc, 1.0f);
        lsh += (a[2] + a[3]) * 0.5f + a[4] / fmaxf(nc, 1.0f);
    }
    gp *= 0.125f; gn *= 0.125f; lsh *= 0.125f;
    float lgeo = gp + gn;
    float lgw = (0.5f * lgeo + 0.5f * lsh) * 0.5f;
    float clp = ws[OFF_ACCCL + 0] / 8.0f;
    float cln = ws[OFF_ACCCL + 1] / (8.0f * 2040.0f);
    float lcl = (clp + cln) * 0.5f * 0.5f;
    out[OUT_SCAL + 0] = lgw + lcl;  // total
    out[OUT_SCAL + 1] = gp;         // geo_pos_loss
    out[OUT_SCAL + 2] = gn;         // geo_neg_loss
    out[OUT_SCAL + 3] = lsh;        // loss_sharp
    out[OUT_SCAL + 4] = lcl;        // loss_cl
}

extern "C" void kernel_launch(void* const* d_in, const int* in_sizes, int n_in,
                              void* d_out, int out_size, void* d_ws, size_t ws_size,
                              hipStream_t stream) {
    const float* q_geo   = (const float*)d_in[0];
    const float* q_cl    = (const float*)d_in[1];
    const float* geo_pos = (const float*)d_in[2];
    const float* cl_pos  = (const float*)d_in[3];
    const int*   label   = (const int*)d_in[4];
    const int*   idx     = (const int*)d_in[5];
    float* out = (float*)d_out;
    float* ws  = (float*)d_ws;

    gemm_stats<<<dim3(1025), dim3(256), 0, stream>>>(q_geo, geo_pos, q_cl, cl_pos, idx, out, ws);
    mid<<<dim3(528), dim3(256), 0, stream>>>(cl_pos, idx, ws, out);
    loss_recompute<<<dim3(1024), dim3(256), 0, stream>>>(q_geo, geo_pos, label, out, ws);
    finalize<<<dim3(1), dim3(64), 0, stream>>>(out, ws);
}

// Round 4
// 147.376 us; speedup vs baseline: 1.3663x; 1.3663x over previous
//
#include <hip/hip_runtime.h>
#include <math.h>

// Problem constants
#define BB 8
#define LL 1024
#define SS 1024
#define CC 128
#define NN 8
#define PP 256

static constexpr float EPS       = 1e-6f;
static constexpr float ONE_M_EPS = 1.0f - 1e-6f;
static constexpr float INV_T     = 1.0f / 0.07f;
static constexpr float NLL_MAX   = 13.815511f;    // -log(1e-6)
static constexpr float NLL_MIN   = 1.0000005e-6f; // -log(1-1e-6)

// Workspace layout (float offsets) — identical to round-2 (dot stored)
static constexpr size_t DOTSZ      = (size_t)BB * LL * SS;   // 8388608
static constexpr size_t OFF_LSER   = DOTSZ;                  // B*L
static constexpr size_t OFF_LSEC   = DOTSZ + 16384;          // B*S
static constexpr size_t OFF_SHARP2 = DOTSZ + 32768;          // B*L
static constexpr size_t OFF_RP     = DOTSZ + 40960;          // rowpart: 8*16*1024*4
static constexpr size_t OFF_CP     = OFF_RP + 524288;        // colpart: 8*16*1024*4
static constexpr size_t OFF_ACC    = OFF_CP + 524288;        // B*6
static constexpr size_t OFF_ACCCL  = OFF_ACC + 48;           // 2
static constexpr size_t OFF_QN     = OFF_ACC + 64;           // 8*128 normalized q_sel

// Output layout (floats): sharp1[8192], cl_pos_save[1024], scalars
static constexpr int OUT_CLSAVE = 8192;
static constexpr int OUT_SCAL   = 9216;

typedef __bf16 bf16x8 __attribute__((ext_vector_type(8)));
typedef float  floatx4 __attribute__((ext_vector_type(4)));

__device__ __forceinline__ bf16x8 mkfrag(unsigned a, unsigned b, unsigned c, unsigned d) {
    uint4 t = make_uint4(a, b, c, d);
    return __builtin_bit_cast(bf16x8, t);
}

// Split 4 fp32 into packed bf16 hi pairs (RNE) + lo pairs (exact residual).
__device__ __forceinline__ void split_f4(float4 x,
                                         unsigned& hp0, unsigned& hp1,
                                         unsigned& lp0, unsigned& lp1) {
    unsigned u0 = __builtin_bit_cast(unsigned, x.x);
    unsigned u1 = __builtin_bit_cast(unsigned, x.y);
    unsigned u2 = __builtin_bit_cast(unsigned, x.z);
    unsigned u3 = __builtin_bit_cast(unsigned, x.w);
    unsigned r0 = u0 + 0x7FFFu + ((u0 >> 16) & 1u);
    unsigned r1 = u1 + 0x7FFFu + ((u1 >> 16) & 1u);
    unsigned r2 = u2 + 0x7FFFu + ((u2 >> 16) & 1u);
    unsigned r3 = u3 + 0x7FFFu + ((u3 >> 16) & 1u);
    float s0 = x.x - __builtin_bit_cast(float, r0 & 0xFFFF0000u);
    float s1 = x.y - __builtin_bit_cast(float, r1 & 0xFFFF0000u);
    float s2 = x.z - __builtin_bit_cast(float, r2 & 0xFFFF0000u);
    float s3 = x.w - __builtin_bit_cast(float, r3 & 0xFFFF0000u);
    hp0 = __builtin_amdgcn_perm(r1, r0, 0x07060302u);
    hp1 = __builtin_amdgcn_perm(r3, r2, 0x07060302u);
    lp0 = __builtin_amdgcn_perm(__builtin_bit_cast(unsigned, s1),
                                __builtin_bit_cast(unsigned, s0), 0x07060302u);
    lp1 = __builtin_amdgcn_perm(__builtin_bit_cast(unsigned, s3),
                                __builtin_bit_cast(unsigned, s2), 0x07060302u);
}

// Read an 8-float fragment (k = q*8..q*8+7) from a swizzled LDS tile row and split.
// LDS tile: [128 rows][32 floats]; 16B chunk c stored at physical chunk c^(row&7).
__device__ __forceinline__ void frag_from_lds(const float* tile, int row, int q,
                                              bf16x8& hi, bf16x8& lo) {
    const float* rp = tile + row * 32;
    int sw = row & 7;
    float4 x0 = *(const float4*)(rp + (((q * 2)     ^ sw) * 4));
    float4 x1 = *(const float4*)(rp + (((q * 2 + 1) ^ sw) * 4));
    unsigned h0, h1, h2, h3, l0, l1, l2, l3;
    split_f4(x0, h0, h1, l0, l1);
    split_f4(x1, h2, h3, l2, l3);
    hi = mkfrag(h0, h1, h2, h3);
    lo = mkfrag(l0, l1, l2, l3);
}

// ---------------- K1: LDS-tiled GEMM (blocks 0..511) + prep (block 512) ----------------
// 128x128 tile per block, 4 waves (each 64x64), BK=32 fp32 double-buffered in LDS.
__global__ __launch_bounds__(256, 2) void gemm_dot(const float* __restrict__ A,
                                                   const float* __restrict__ Bm,
                                                   const float* __restrict__ q_cl,
                                                   const float* __restrict__ cl_pos,
                                                   const int* __restrict__ idx,
                                                   float* __restrict__ out,
                                                   float* __restrict__ dot,
                                                   float* __restrict__ ws) {
    __shared__ __align__(16) float ldsA[2][128 * 32];   // 2 x 16KB
    __shared__ __align__(16) float ldsB[2][128 * 32];   // 2 x 16KB

    int tid  = threadIdx.x;
    int lane = tid & 63;
    int w    = tid >> 6;

    if (blockIdx.x == 512) {
        // ---- prep: zero accumulators, normalize q_sel, write cl_pos_save ----
        if (tid < 52) ws[OFF_ACC + tid] = 0.0f;
        for (int n = w; n < NN; n += 4) {
            int in = idx[n];
            const float* q = q_cl + ((size_t)(n * PP + in)) * CC;
            float2 qv = *(const float2*)(q + 2 * lane);
            float ss = qv.x * qv.x + qv.y * qv.y;
            for (int o = 32; o; o >>= 1) ss += __shfl_xor(ss, o);
            float inv = 1.0f / fmaxf(sqrtf(ss), 1e-12f);
            *(float2*)(ws + OFF_QN + n * 128 + 2 * lane) = make_float2(qv.x * inv, qv.y * inv);
            const float* cp = cl_pos + ((size_t)(n * PP + in)) * CC;
            float2 cv = *(const float2*)(cp + 2 * lane);
            *(float2*)(out + OUT_CLSAVE + n * 128 + 2 * lane) = cv;
        }
        return;
    }

    int t  = blockIdx.x;            // 0..511
    int b  = t >> 6;
    int rm = t & 63;
    int bl = rm >> 3, bs = rm & 7;
    int R0 = bl * 128, C0 = bs * 128;

    const float* Ab = A  + ((size_t)b * LL + R0) * CC;
    const float* Bb = Bm + ((size_t)b * SS + C0) * CC;

    // Staging assignment: waves 0,1 -> A ; waves 2,3 -> B. Combined lane L = 0..127.
    // Piece i (0..7): row = i*16 + (L>>3), 16B chunk = L&7, swizzled into LDS.
    const float* src  = (w >= 2) ? Bb : Ab;
    float* dst0 = (w >= 2) ? ldsB[0] : ldsA[0];
    float* dst1 = (w >= 2) ? ldsB[1] : ldsA[1];
    int L       = ((w & 1) << 6) | lane;
    int rowoff  = L >> 3;                       // 0..15
    int chunk   = L & 7;
    int swz4    = (chunk ^ (rowoff & 7)) * 4;   // physical chunk offset (floats)

    int fl   = lane & 15;
    int quad = lane >> 4;
    int wr   = w >> 1, wc = w & 1;              // wave's 64x64 quadrant
    int Rw   = wr * 64, Cw = wc * 64;           // local bases

    floatx4 acc[4][4];
#pragma unroll
    for (int i = 0; i < 4; i++)
#pragma unroll
        for (int j = 0; j < 4; j++) acc[i][j] = (floatx4){0.f, 0.f, 0.f, 0.f};

    float4 rg[8];
    // prologue: stage k-step 0
#pragma unroll
    for (int i = 0; i < 8; i++)
        rg[i] = *(const float4*)(src + (size_t)(i * 16 + rowoff) * CC + chunk * 4);
#pragma unroll
    for (int i = 0; i < 8; i++)
        *(float4*)(dst0 + (i * 16 + rowoff) * 32 + swz4) = rg[i];
    __syncthreads();

    for (int ks = 0; ks < 4; ks++) {
        const float* la = (ks & 1) ? ldsA[1] : ldsA[0];
        const float* lb = (ks & 1) ? ldsB[1] : ldsB[0];
        float* nxt = ((ks + 1) & 1) ? dst1 : dst0;
        if (ks < 3) {
            int k0 = (ks + 1) * 32;
#pragma unroll
            for (int i = 0; i < 8; i++)
                rg[i] = *(const float4*)(src + (size_t)(i * 16 + rowoff) * CC + k0 + chunk * 4);
        }
        // compute current buffer
        bf16x8 ah[4], al[4];
#pragma unroll
        for (int mt = 0; mt < 4; mt++)
            frag_from_lds(la, Rw + mt * 16 + fl, quad, ah[mt], al[mt]);
#pragma unroll
        for (int nt = 0; nt < 4; nt++) {
            bf16x8 bh, blo;
            frag_from_lds(lb, Cw + nt * 16 + fl, quad, bh, blo);
#pragma unroll
            for (int mt = 0; mt < 4; mt++) {
                acc[mt][nt] = __builtin_amdgcn_mfma_f32_16x16x32_bf16(ah[mt], bh,  acc[mt][nt], 0, 0, 0);
                acc[mt][nt] = __builtin_amdgcn_mfma_f32_16x16x32_bf16(ah[mt], blo, acc[mt][nt], 0, 0, 0);
                acc[mt][nt] = __builtin_amdgcn_mfma_f32_16x16x32_bf16(al[mt], bh,  acc[mt][nt], 0, 0, 0);
            }
        }
        if (ks < 3) {
#pragma unroll
            for (int i = 0; i < 8; i++)
                *(float4*)(nxt + (i * 16 + rowoff) * 32 + swz4) = rg[i];
        }
        __syncthreads();
    }

    // ---- Store dot tile. C/D layout: col=lane&15, row=quad*4+reg ----
#pragma unroll
    for (int mt = 0; mt < 4; mt++)
#pragma unroll
        for (int nt = 0; nt < 4; nt++) {
            int col = C0 + Cw + nt * 16 + fl;
#pragma unroll
            for (int r = 0; r < 4; r++) {
                int row = R0 + Rw + mt * 16 + quad * 4 + r;
                dot[((size_t)(b * 1024 + row)) * 1024 + col] = acc[mt][nt][r];
            }
        }

    // ---- Fused wave-private tile statistics (64x64 per wave, as round-2) ----
    int stile = bs * 2 + wc;    // 64-col tile index 0..15
    int ltile = bl * 2 + wr;    // 64-row tile index 0..15
    float ces[4], cmx[4], csm[4], csq[4];
#pragma unroll
    for (int nt = 0; nt < 4; nt++) { ces[nt] = 0.f; cmx[nt] = -1e30f; csm[nt] = 0.f; csq[nt] = 0.f; }
#pragma unroll
    for (int mt = 0; mt < 4; mt++) {
#pragma unroll
        for (int r = 0; r < 4; r++) {
            float es = 0.f, mx = -1e30f, sm = 0.f, sq = 0.f;
#pragma unroll
            for (int nt = 0; nt < 4; nt++) {
                float d  = acc[mt][nt][r];
                float e  = __expf(d * INV_T);
                float s2 = fmaf(0.5f, d, 0.5f);
                es += e; mx = fmaxf(mx, s2); sm += s2; sq += s2 * s2;
                ces[nt] += e; cmx[nt] = fmaxf(cmx[nt], s2); csm[nt] += s2; csq[nt] += s2 * s2;
            }
            for (int o = 1; o < 16; o <<= 1) {
                es += __shfl_xor(es, o);
                mx = fmaxf(mx, __shfl_xor(mx, o));
                sm += __shfl_xor(sm, o);
                sq += __shfl_xor(sq, o);
            }
            if (fl == 0) {
                int row = R0 + Rw + mt * 16 + quad * 4 + r;
                *(float4*)(ws + OFF_RP + (((size_t)(b * 16 + stile)) * 1024 + row) * 4) =
                    make_float4(es, mx, sm, sq);
            }
        }
    }
#pragma unroll
    for (int nt = 0; nt < 4; nt++) {
        float es = ces[nt], mx = cmx[nt], sm = csm[nt], sq = csq[nt];
        for (int o = 16; o < 64; o <<= 1) {
            es += __shfl_xor(es, o);
            mx = fmaxf(mx, __shfl_xor(mx, o));
            sm += __shfl_xor(sm, o);
            sq += __shfl_xor(sq, o);
        }
        if (quad == 0) {
            int col = C0 + Cw + nt * 16 + fl;
            *(float4*)(ws + OFF_CP + (((size_t)(b * 16 + ltile)) * 1024 + col) * 4) =
                make_float4(es, mx, sm, sq);
        }
    }
}

// ---------------- K2: blocks 0..15 combine+softmax; blocks 16..527 contrast ----------------
__global__ __launch_bounds__(256) void mid(const float* __restrict__ cl_pos,
                                           const int* __restrict__ idx,
                                           float* __restrict__ ws,
                                           float* __restrict__ out) {
    int q   = blockIdx.x;
    int tid = threadIdx.x;
    int lane = tid & 63, wid = tid >> 6;

    if (q < 16) {
        bool docol = (q < 8);
        int b = q & 7;
        const float* part = ws + (docol ? OFF_CP : OFF_RP);
        float* lse = ws + (docol ? OFF_LSEC : OFF_LSER) + (size_t)b * 1024;
        float zs[4];
        float mxall = -1e30f;
#pragma unroll
        for (int r = 0; r < 4; r++) {
            int i = tid + r * 256;
            float es = 0.f, mx = -1e30f, sm = 0.f, sq = 0.f;
#pragma unroll
            for (int t = 0; t < 16; t++) {
                float4 v = *(const float4*)(part + (((size_t)(b * 16 + t)) * 1024 + i) * 4);
                es += v.x; mx = fmaxf(mx, v.y); sm += v.z; sq += v.w;
            }
            float mean = sm * (1.0f / 1024.0f);
            float var  = (sq - sm * sm * (1.0f / 1024.0f)) * (1.0f / 1023.0f);
            zs[r] = (mx - mean) / sqrtf(fmaxf(var, 1e-30f));
            mxall = fmaxf(mxall, zs[r]);
            lse[i] = __logf(es);
        }
        __shared__ float sb[4];
        __shared__ float red;
        float mx = mxall;
        for (int o = 32; o; o >>= 1) mx = fmaxf(mx, __shfl_xor(mx, o));
        if (!lane) sb[wid] = mx;
        __syncthreads();
        if (tid == 0) red = fmaxf(fmaxf(sb[0], sb[1]), fmaxf(sb[2], sb[3]));
        __syncthreads();
        mx = red;
        float e[4]; float smv = 0.f;
#pragma unroll
        for (int r = 0; r < 4; r++) { e[r] = __expf(zs[r] - mx); smv += e[r]; }
        for (int o = 32; o; o >>= 1) smv += __shfl_xor(smv, o);
        __syncthreads();
        if (!lane) sb[wid] = smv;
        __syncthreads();
        if (tid == 0) red = sb[0] + sb[1] + sb[2] + sb[3];
        __syncthreads();
        float inv = 1.0f / red;
        float* dst = docol ? (out + (size_t)b * 1024) : (ws + OFF_SHARP2 + (size_t)b * 1024);
#pragma unroll
        for (int r = 0; r < 4; r++) dst[tid + r * 256] = e[r] * inv;
    } else {
        // ---- contrast: one wave per all_k row j ----
        int j = (q - 16) * 4 + wid;
        int m, p;
        if (j < NN) {
            m = j; p = idx[j];
        } else {
            int jj = j - NN;
            m = jj / (PP - 1);
            p = 1 + (jj - m * (PP - 1));
            if (p == idx[m]) p = 0;
        }
        const float* k = cl_pos + ((size_t)(m * PP + p)) * CC;
        float2 kv = *(const float2*)(k + 2 * lane);
        float ksq = kv.x * kv.x + kv.y * kv.y;
        for (int o = 32; o; o >>= 1) ksq += __shfl_xor(ksq, o);
        float invkn = 1.0f / fmaxf(sqrtf(ksq), 1e-12f);
        float pos = 0.0f, neg = 0.0f;
        if (j < NN) {
            const float2 qv = *(const float2*)(ws + OFF_QN + j * 128 + 2 * lane);
            float dt = qv.x * kv.x + qv.y * kv.y;
            for (int o = 32; o; o >>= 1) dt += __shfl_xor(dt, o);
            float sim = fminf(fmaxf(fmaf(0.5f * invkn, dt, 0.5f), EPS), ONE_M_EPS);
            pos = -__logf(sim);
        } else {
#pragma unroll
            for (int n = 0; n < NN; n++) {
                const float2 qv = *(const float2*)(ws + OFF_QN + n * 128 + 2 * lane);
                float dt = qv.x * kv.x + qv.y * kv.y;
                for (int o = 32; o; o >>= 1) dt += __shfl_xor(dt, o);
                float om = fminf(fmaxf(fmaf(-0.5f * invkn, dt, 0.5f), EPS), ONE_M_EPS);
                neg -= __logf(om);
            }
        }
        __shared__ float cb[2][4];
        if (!lane) { cb[0][wid] = pos; cb[1][wid] = neg; }
        __syncthreads();
        if (tid == 0) {
            float ps = cb[0][0] + cb[0][1] + cb[0][2] + cb[0][3];
            float ng = cb[1][0] + cb[1][1] + cb[1][2] + cb[1][3];
            if (ps != 0.0f) atomicAdd(ws + OFF_ACCCL + 0, ps);
            if (ng != 0.0f) atomicAdd(ws + OFF_ACCCL + 1, ng);
        }
    }
}

// ---------------- K3: main elementwise loss (branchless, identical to round-2) ----------------
__device__ __forceinline__ void proc_elem(float d, int lab, float lcj, float sh1j,
                                          float lr, float s2v,
                                          float& posg, float& negg, float& l1, float& l2,
                                          float& negs, float& pcf) {
    float t = lr + lcj - d * (2.0f * INV_T);   // -log(conf_geo)
    float isPos = (lab == 1) ? 1.0f : 0.0f;
    float isNeg = 1.0f - isPos;
    float tp   = fminf(fmaxf(t, NLL_MIN), NLL_MAX);
    float simc = fminf(fmaxf(fmaf(0.5f, d, 0.5f), EPS), ONE_M_EPS);
    float om   = fminf(fmaxf(fmaf(-0.5f, d, 0.5f), EPS), ONE_M_EPS);   // 1-simc exactly
    float nll2 = -__logf(simc);
    float cf   = fminf(fmaxf(__expf(-t), EPS), ONE_M_EPS);
    float nllg = -__logf(1.0f - cf);
    float nlls = -__logf(om);
    posg += isPos * tp;
    l1   += isPos * nll2 * sh1j;
    l2   += isPos * nll2 * s2v;
    pcf  += isPos;
    negg += isNeg * nllg;
    negs += isNeg * nlls;
}

__global__ __launch_bounds__(256) void main_loss(const float* __restrict__ dot,
                                                 const int* __restrict__ label,
                                                 const float* __restrict__ sharp1,
                                                 float* __restrict__ ws) {
    int b = blockIdx.y;
    int l0 = blockIdx.x * 4;
    int s = threadIdx.x * 4;
    float4 lc4 = *(const float4*)(ws + OFF_LSEC + (size_t)b * 1024 + s);
    float4 sh1 = *(const float4*)(sharp1 + (size_t)b * 1024 + s);
    const float* lser = ws + OFF_LSER + (size_t)b * 1024;
    const float* sh2  = ws + OFF_SHARP2 + (size_t)b * 1024;
    float posg = 0, negg = 0, l1 = 0, l2 = 0, negs = 0, pcf = 0;
#pragma unroll
    for (int r = 0; r < 4; r++) {
        int l = l0 + r;
        float lr  = lser[l];
        float s2v = sh2[l];
        size_t base = ((size_t)(b * 1024 + l)) * 1024 + s;
        float4 d4 = *(const float4*)(dot + base);
        int4  lb  = *(const int4*)(label + base);
        proc_elem(d4.x, lb.x, lc4.x, sh1.x, lr, s2v, posg, negg, l1, l2, negs, pcf);
        proc_elem(d4.y, lb.y, lc4.y, sh1.y, lr, s2v, posg, negg, l1, l2, negs, pcf);
        proc_elem(d4.z, lb.z, lc4.z, sh1.z, lr, s2v, posg, negg, l1, l2, negs, pcf);
        proc_elem(d4.w, lb.w, lc4.w, sh1.w, lr, s2v, posg, negg, l1, l2, negs, pcf);
    }
    float vals[6] = {posg, negg, l1, l2, negs, pcf};
    __shared__ float sb[6][4];
    int lane = threadIdx.x & 63, wid = threadIdx.x >> 6;
#pragma unroll
    for (int k = 0; k < 6; k++) {
        float v = vals[k];
        for (int o = 32; o; o >>= 1) v += __shfl_xor(v, o);
        if (!lane) sb[k][wid] = v;
    }
    __syncthreads();
    if (threadIdx.x < 6) {
        float r = sb[threadIdx.x][0] + sb[threadIdx.x][1] + sb[threadIdx.x][2] + sb[threadIdx.x][3];
        atomicAdd(ws + OFF_ACC + (size_t)b * 6 + threadIdx.x, r);
    }
}

// ---------------- K4: final scalar combine ----------------
__global__ void finalize(float* __restrict__ out, const float* __restrict__ ws) {
    if (threadIdx.x != 0) return;
    float gp = 0, gn = 0, lsh = 0;
    for (int b = 0; b < 8; b++) {
        const float* a = ws + OFF_ACC + (size_t)b * 6;
        float pc = a[5];
        float nc = (float)((size_t)LL * SS) - pc;
        gp += a[0] / fmaxf(pc, 1.0f);
        gn += a[1] / fmaxf(nc, 1.0f);
        lsh += (a[2] + a[3]) * 0.5f + a[4] / fmaxf(nc, 1.0f);
    }
    gp *= 0.125f; gn *= 0.125f; lsh *= 0.125f;
    float lgeo = gp + gn;
    float lgw = (0.5f * lgeo + 0.5f * lsh) * 0.5f;
    float clp = ws[OFF_ACCCL + 0] / 8.0f;
    float cln = ws[OFF_ACCCL + 1] / (8.0f * 2040.0f);
    float lcl = (clp + cln) * 0.5f * 0.5f;
    out[OUT_SCAL + 0] = lgw + lcl;  // total
    out[OUT_SCAL + 1] = gp;         // geo_pos_loss
    out[OUT_SCAL + 2] = gn;         // geo_neg_loss
    out[OUT_SCAL + 3] = lsh;        // loss_sharp
    out[OUT_SCAL + 4] = lcl;        // loss_cl
}

extern "C" void kernel_launch(void* const* d_in, const int* in_sizes, int n_in,
                              void* d_out, int out_size, void* d_ws, size_t ws_size,
                              hipStream_t stream) {
    const float* q_geo   = (const float*)d_in[0];
    const float* q_cl    = (const float*)d_in[1];
    const float* geo_pos = (const float*)d_in[2];
    const float* cl_pos  = (const float*)d_in[3];
    const int*   label   = (const int*)d_in[4];
    const int*   idx     = (const int*)d_in[5];
    float* out = (float*)d_out;
    float* ws  = (float*)d_ws;
    float* dot = ws;

    gemm_dot<<<dim3(513), dim3(256), 0, stream>>>(q_geo, geo_pos, q_cl, cl_pos, idx, out, dot, ws);
    mid<<<dim3(528), dim3(256), 0, stream>>>(cl_pos, idx, ws, out);
    main_loss<<<dim3(256, 8), dim3(256), 0, stream>>>(dot, label, out, ws);
    finalize<<<dim3(1), dim3(64), 0, stream>>>(out, ws);
}